// Round 4
// baseline (100.165 us; speedup 1.0000x reference)
//
#include <hip/hip_runtime.h>
#include <hip/hip_bf16.h>

#define N_ROWS 8192
#define DIM 256
#define TEMP_INV 20.0f
// exp(cos/T) = exp2(cos * 20*log2(e)); anchor rows are PRE-SCALED by this so
// the fused epilogue is a bare v_exp on the MFMA accumulator.
#define EXP_SCALE 28.853900817779268f

typedef __attribute__((ext_vector_type(8))) short bf16x8;
typedef __attribute__((ext_vector_type(4))) float f32x4;

// ---------------------------------------------------------------------------
// 1a) Anchor rows: L2-normalize, scale by EXP_SCALE, row-major bf16.
// ---------------------------------------------------------------------------
__global__ void __launch_bounds__(256) norm_a_kernel(
    const float* __restrict__ anc, __hip_bfloat16* __restrict__ a_n) {
  int wid = (blockIdx.x * 256 + threadIdx.x) >> 6;   // row 0..8191
  int lane = threadIdx.x & 63;
  float4 v = reinterpret_cast<const float4*>(anc + (size_t)wid * DIM)[lane];
  float ss = v.x * v.x + v.y * v.y + v.z * v.z + v.w * v.w;
#pragma unroll
  for (int m = 32; m; m >>= 1) ss += __shfl_xor(ss, m);
  float scale = EXP_SCALE / fmaxf(sqrtf(ss), 1e-8f);
  union { __hip_bfloat16 h[4]; uint2 u; } pk;
  pk.h[0] = __float2bfloat16(v.x * scale);
  pk.h[1] = __float2bfloat16(v.y * scale);
  pk.h[2] = __float2bfloat16(v.z * scale);
  pk.h[3] = __float2bfloat16(v.w * scale);
  reinterpret_cast<uint2*>(a_n + (size_t)wid * DIM)[lane] = pk.u;
}

// ---------------------------------------------------------------------------
// 1b) P/N rows: L2-normalize + transpose into k-major panels.
//     Panel = 32 cols; chunk (16B = 8 bf16 of consecutive k) index within
//     panel = k0*32 + col  (k0 = k/8).  Fused-kernel reads of this layout are
//     perfectly linear in lane -> zero LDS bank conflicts, and staging is a
//     contiguous 16KB global_load_lds.
//     Block: 256 thr, one panel. LDS-write transpose conflicts are paid here
//     (tiny kernel) instead of in the GEMM loop.
// ---------------------------------------------------------------------------
__global__ void __launch_bounds__(256) norm_t_kernel(
    const float* __restrict__ pos, const float* __restrict__ neg,
    __hip_bfloat16* __restrict__ p_k, __hip_bfloat16* __restrict__ n_k) {
  __shared__ __align__(16) __hip_bfloat16 t[32 * DIM];   // 16KB k-major panel
  const int b = blockIdx.x;                 // 0..511
  const float* src = (b < 256) ? pos : neg;
  __hip_bfloat16* dst = (b < 256) ? p_k : n_k;
  const int pb = b & 255;
  const int lane = threadIdx.x & 63;
  const int w = threadIdx.x >> 6;
#pragma unroll
  for (int i = 0; i < 8; ++i) {
    int r = i * 4 + w;                       // row (col of B) within panel
    float4 v = reinterpret_cast<const float4*>(src + (size_t)(pb * 32 + r) * DIM)[lane];
    float ss = v.x * v.x + v.y * v.y + v.z * v.z + v.w * v.w;
#pragma unroll
    for (int m = 32; m; m >>= 1) ss += __shfl_xor(ss, m);
    float scale = 1.0f / fmaxf(sqrtf(ss), 1e-8f);
    union { __hip_bfloat16 h[4]; uint2 u; } pk;
    pk.h[0] = __float2bfloat16(v.x * scale);
    pk.h[1] = __float2bfloat16(v.y * scale);
    pk.h[2] = __float2bfloat16(v.z * scale);
    pk.h[3] = __float2bfloat16(v.w * scale);
    // lane holds k = 4*lane..4*lane+3  ->  k0 = lane>>1, half = lane&1
    char* p = (char*)t + ((((lane >> 1) * 32) + r) << 4) + ((lane & 1) << 3);
    *reinterpret_cast<uint2*>(p) = pk.u;
  }
  __syncthreads();
  const uint4* ts = reinterpret_cast<const uint4*>(t);
  uint4* out = reinterpret_cast<uint4*>(dst + (size_t)pb * (32 * DIM));
#pragma unroll
  for (int j = 0; j < 4; ++j)
    out[threadIdx.x + j * 256] = ts[threadIdx.x + j * 256];
}

// ---------------------------------------------------------------------------
// 2) diag[i] = cos(anc_i, pos_i)/TEMP from the f32 ORIGINALS (decoupled from
//    the staged bf16 formats; also more accurate). Zero-inits rowsum.
// ---------------------------------------------------------------------------
__global__ void __launch_bounds__(256) diag_kernel(
    const float* __restrict__ anc, const float* __restrict__ pos,
    float* __restrict__ diag, float* __restrict__ rowsum) {
  int wid = (blockIdx.x * 256 + threadIdx.x) >> 6;   // row 0..8191
  int lane = threadIdx.x & 63;
  float4 a = reinterpret_cast<const float4*>(anc + (size_t)wid * DIM)[lane];
  float4 p = reinterpret_cast<const float4*>(pos + (size_t)wid * DIM)[lane];
  float d  = a.x * p.x + a.y * p.y + a.z * p.z + a.w * p.w;
  float na = a.x * a.x + a.y * a.y + a.z * a.z + a.w * a.w;
  float np = p.x * p.x + p.y * p.y + p.z * p.z + p.w * p.w;
#pragma unroll
  for (int m = 32; m; m >>= 1) {
    d  += __shfl_xor(d, m);
    na += __shfl_xor(na, m);
    np += __shfl_xor(np, m);
  }
  if (lane == 0) {
    diag[wid] = TEMP_INV * d /
                (fmaxf(sqrtf(na), 1e-8f) * fmaxf(sqrtf(np), 1e-8f));
    rowsum[wid] = 0.f;
  }
}

// ---------------------------------------------------------------------------
// 3) Fused GEMM + row-wise sum(exp2(logit)).
//    Grid: 16 row-blocks (BM=512) x 32 col-chunks (512 cols = 16 panels).
//    Block: 512 thr = 8 waves; wave owns 64 rows: A = 4 row-frags x K=256 in
//    registers (128 VGPR, asm-pinned). Each B frag feeds 4 MFMA (1:4
//    read:MFMA). B panels staged whole (contiguous 16KB global_load_lds,
//    linear src+dst), double-buffered. k-major layout makes every
//    ds_read_b128 linear-in-lane: zero bank conflicts by construction.
//    MFMA 16x16x32_bf16 C layout: col=lane&15, row=(lane>>4)*4+q  [verified].
// ---------------------------------------------------------------------------
__global__ void __launch_bounds__(512, 2) fused_kernel(
    const __hip_bfloat16* __restrict__ a_n, const __hip_bfloat16* __restrict__ p_k,
    const __hip_bfloat16* __restrict__ n_k, float* __restrict__ rowsum) {
  __shared__ __align__(16) __hip_bfloat16 smem[2][32 * DIM];   // 2 x 16KB
  const int tid  = threadIdx.x;
  const int lane = tid & 63;
  const int w    = tid >> 6;          // 0..7
  const int rb   = blockIdx.x >> 5;   // 0..15 (512 rows each)
  const int cc   = blockIdx.x & 31;   // 0..31 (512 cols = 16 panels each)
  const __hip_bfloat16* B = (cc < 16)
      ? (p_k + (size_t)cc * 16 * (32 * DIM))
      : (n_k + (size_t)(cc - 16) * 16 * (32 * DIM));
  const int row0 = rb * 512 + w * 64;
  const int ar = lane & 15;           // fragment row/col index
  const int g  = lane >> 4;           // k-group within fragment

  // A fragments: 64 rows x K=256, register-resident (128 VGPR, pinned).
  bf16x8 afrag[4][8];
#pragma unroll
  for (int rf = 0; rf < 4; ++rf)
#pragma unroll
    for (int kk = 0; kk < 8; ++kk) {
      afrag[rf][kk] = *reinterpret_cast<const bf16x8*>(
          a_n + (size_t)(row0 + rf * 16 + ar) * DIM + kk * 32 + g * 8);
      asm volatile("" : "+v"(afrag[rf][kk]));   // non-remat def: stays in regs
    }

  // Stage panel `it` (16384 B, contiguous) into smem[buf]: linear src+dst.
#define STAGE(buf, it)                                                         \
  {                                                                            \
    _Pragma("unroll")                                                          \
    for (int ch = 0; ch < 2; ++ch) {                                           \
      const char* src = (const char*)B + (size_t)(it) * 16384 + (ch << 13) + (tid << 4); \
      char* dst = (char*)(&smem[buf][0]) + (ch << 13) + (w << 10);             \
      __builtin_amdgcn_global_load_lds(                                        \
          (const __attribute__((address_space(1))) void*)src,                  \
          (__attribute__((address_space(3))) void*)dst, 16, 0, 0);             \
    }                                                                          \
  }

  float psum[4][4];
#pragma unroll
  for (int rf = 0; rf < 4; ++rf)
#pragma unroll
    for (int q = 0; q < 4; ++q) psum[rf][q] = 0.f;

  STAGE(0, 0);
  __syncthreads();
  int cur = 0;
  for (int it = 0; it < 16; ++it) {
    if (it < 15) STAGE(cur ^ 1, it + 1);   // prefetch next panel (overlaps MFMA)
    const char* bb = (const char*)(&smem[cur][0]) + (g << 9) + (ar << 4);
#pragma unroll
    for (int cf = 0; cf < 2; ++cf) {
      f32x4 acc[4];
#pragma unroll
      for (int rf = 0; rf < 4; ++rf) acc[rf] = (f32x4){0.f, 0.f, 0.f, 0.f};
#pragma unroll
      for (int kk = 0; kk < 8; ++kk) {
        // chunk (k0 = kk*4+g, col = cf*16+ar): byte = kk*2048 + g*512 + cf*256 + ar*16
        bf16x8 bf = *reinterpret_cast<const bf16x8*>(bb + (kk << 11) + (cf << 8));
#pragma unroll
        for (int rf = 0; rf < 4; ++rf)
          acc[rf] = __builtin_amdgcn_mfma_f32_16x16x32_bf16(afrag[rf][kk], bf, acc[rf], 0, 0, 0);
      }
      // acc = cos * 20*log2(e): logits bounded -> direct exp2, no max needed.
#pragma unroll
      for (int rf = 0; rf < 4; ++rf)
#pragma unroll
        for (int q = 0; q < 4; ++q)
          psum[rf][q] += __builtin_amdgcn_exp2f(acc[rf][q]);
    }
    __syncthreads();
    cur ^= 1;
  }

  // Reduce over the 16 column-lanes (vary ar, keep g) and accumulate per row.
#pragma unroll
  for (int rf = 0; rf < 4; ++rf)
#pragma unroll
    for (int q = 0; q < 4; ++q) {
      float s = psum[rf][q];
      s += __shfl_xor(s, 1);
      s += __shfl_xor(s, 2);
      s += __shfl_xor(s, 4);
      s += __shfl_xor(s, 8);
      if (ar == 0)
        atomicAdd(rowsum + row0 + rf * 16 + g * 4 + q, s);
    }
}

// ---------------------------------------------------------------------------
// 4) loss = mean_i( log(rowsum[i]) - diag[i] )
// ---------------------------------------------------------------------------
__global__ void __launch_bounds__(256) loss_kernel(
    const float* __restrict__ rowsum, const float* __restrict__ diag,
    float* __restrict__ out) {
  __shared__ float sh[4];
  float acc = 0.f;
  for (int i = threadIdx.x; i < N_ROWS; i += 256)
    acc += logf(rowsum[i]) - diag[i];
#pragma unroll
  for (int m = 32; m; m >>= 1) acc += __shfl_xor(acc, m);
  if ((threadIdx.x & 63) == 0) sh[threadIdx.x >> 6] = acc;
  __syncthreads();
  if (threadIdx.x == 0) out[0] = (sh[0] + sh[1] + sh[2] + sh[3]) / (float)N_ROWS;
}

// ---------------------------------------------------------------------------
extern "C" void kernel_launch(void* const* d_in, const int* in_sizes, int n_in,
                              void* d_out, int out_size, void* d_ws, size_t ws_size,
                              hipStream_t stream) {
  const float* anc = (const float*)d_in[0];
  const float* pos = (const float*)d_in[1];
  const float* neg = (const float*)d_in[2];
  char* ws = (char*)d_ws;
  __hip_bfloat16* a_n = (__hip_bfloat16*)ws;                 // [8192][256] bf16 row-major
  __hip_bfloat16* p_k = a_n + (size_t)N_ROWS * DIM;          // k-major panels
  __hip_bfloat16* n_k = p_k + (size_t)N_ROWS * DIM;
  float* diag = (float*)(ws + (size_t)3 * N_ROWS * DIM * 2); // 8192 f32
  float* rowsum = diag + N_ROWS;                             // 8192 f32
  float* out = (float*)d_out;

  norm_a_kernel<<<N_ROWS / 4, 256, 0, stream>>>(anc, a_n);
  norm_t_kernel<<<2 * N_ROWS / 32, 256, 0, stream>>>(pos, neg, p_k, n_k);
  diag_kernel<<<N_ROWS / 4, 256, 0, stream>>>(anc, pos, diag, rowsum);
  fused_kernel<<<16 * 32, 512, 0, stream>>>(a_n, p_k, n_k, rowsum);
  loss_kernel<<<1, 256, 0, stream>>>(rowsum, diag, out);
}

// Round 5
// 93.489 us; speedup vs baseline: 1.0714x; 1.0714x over previous
//
#include <hip/hip_runtime.h>
#include <hip/hip_bf16.h>

#define N_ROWS 8192
#define DIM 256
#define TEMP_INV 20.0f
// exp(cos/T) = exp2(cos * 20*log2(e)); anchor rows are PRE-SCALED by this so
// the fused epilogue is a bare v_exp on the MFMA accumulator.
#define EXP_SCALE 28.853900817779268f

typedef __attribute__((ext_vector_type(8))) short bf16x8;
typedef __attribute__((ext_vector_type(4))) float f32x4;

// ---------------------------------------------------------------------------
// 1) Per anchor row i (one wave per row):
//    - a_n[i] = anc[i] * EXP_SCALE / ||anc[i]||   (bf16, row-major)
//    - diag[i] = cos(anc_i,pos_i)/TEMP  (from f32 originals)
//    - rowsum[i] = 0
// ---------------------------------------------------------------------------
__global__ void __launch_bounds__(256) prep_kernel(
    const float* __restrict__ anc, const float* __restrict__ pos,
    __hip_bfloat16* __restrict__ a_n, float* __restrict__ diag,
    float* __restrict__ rowsum) {
  int wid = (blockIdx.x * 256 + threadIdx.x) >> 6;   // row 0..8191
  int lane = threadIdx.x & 63;
  float4 a = reinterpret_cast<const float4*>(anc + (size_t)wid * DIM)[lane];
  float4 p = reinterpret_cast<const float4*>(pos + (size_t)wid * DIM)[lane];
  float d  = a.x * p.x + a.y * p.y + a.z * p.z + a.w * p.w;
  float na = a.x * a.x + a.y * a.y + a.z * a.z + a.w * a.w;
  float np = p.x * p.x + p.y * p.y + p.z * p.z + p.w * p.w;
#pragma unroll
  for (int m = 32; m; m >>= 1) {
    d  += __shfl_xor(d, m);
    na += __shfl_xor(na, m);
    np += __shfl_xor(np, m);
  }
  float rna = fmaxf(sqrtf(na), 1e-8f);
  float scale = EXP_SCALE / rna;
  union { __hip_bfloat16 h[4]; uint2 u; } pk;
  pk.h[0] = __float2bfloat16(a.x * scale);
  pk.h[1] = __float2bfloat16(a.y * scale);
  pk.h[2] = __float2bfloat16(a.z * scale);
  pk.h[3] = __float2bfloat16(a.w * scale);
  reinterpret_cast<uint2*>(a_n + (size_t)wid * DIM)[lane] = pk.u;
  if (lane == 0) {
    diag[wid] = TEMP_INV * d / (rna * fmaxf(sqrtf(np), 1e-8f));
    rowsum[wid] = 0.f;
  }
}

// ---------------------------------------------------------------------------
// 2) P/N rows: L2-normalize + transpose into k-major panels.
//    Panel = 32 cols; 16B chunk (8 consecutive k) index within panel
//    = k0*32 + col  (k0 = k/8). Fused-kernel reads of this layout are
//    linear-in-lane -> zero LDS bank conflicts; staging is a contiguous
//    16KB global_load_lds. Transpose conflicts are paid here (tiny kernel).
// ---------------------------------------------------------------------------
__global__ void __launch_bounds__(256) norm_t_kernel(
    const float* __restrict__ pos, const float* __restrict__ neg,
    __hip_bfloat16* __restrict__ p_k, __hip_bfloat16* __restrict__ n_k) {
  __shared__ __align__(16) __hip_bfloat16 t[32 * DIM];   // 16KB k-major panel
  const int b = blockIdx.x;                 // 0..511
  const float* src = (b < 256) ? pos : neg;
  __hip_bfloat16* dst = (b < 256) ? p_k : n_k;
  const int pb = b & 255;
  const int lane = threadIdx.x & 63;
  const int w = threadIdx.x >> 6;
#pragma unroll
  for (int i = 0; i < 8; ++i) {
    int r = i * 4 + w;                       // row (col of B) within panel
    float4 v = reinterpret_cast<const float4*>(src + (size_t)(pb * 32 + r) * DIM)[lane];
    float ss = v.x * v.x + v.y * v.y + v.z * v.z + v.w * v.w;
#pragma unroll
    for (int m = 32; m; m >>= 1) ss += __shfl_xor(ss, m);
    float scale = 1.0f / fmaxf(sqrtf(ss), 1e-8f);
    union { __hip_bfloat16 h[4]; uint2 u; } pk;
    pk.h[0] = __float2bfloat16(v.x * scale);
    pk.h[1] = __float2bfloat16(v.y * scale);
    pk.h[2] = __float2bfloat16(v.z * scale);
    pk.h[3] = __float2bfloat16(v.w * scale);
    // lane holds k = 4*lane..4*lane+3  ->  k0 = lane>>1, half = lane&1
    char* p = (char*)t + ((((lane >> 1) * 32) + r) << 4) + ((lane & 1) << 3);
    *reinterpret_cast<uint2*>(p) = pk.u;
  }
  __syncthreads();
  const uint4* ts = reinterpret_cast<const uint4*>(t);
  uint4* out = reinterpret_cast<uint4*>(dst + (size_t)pb * (32 * DIM));
#pragma unroll
  for (int j = 0; j < 4; ++j)
    out[threadIdx.x + j * 256] = ts[threadIdx.x + j * 256];
}

// ---------------------------------------------------------------------------
// 3) Fused GEMM + row-wise sum(exp2(logit)).
//    Grid: 32 row-blocks (BM=256) x 32 col-chunks (512 cols = 16 panels)
//    = 1024 blocks -> 4 blocks/CU (4 independent barrier domains per CU so
//    one block's stage/barrier drain hides under another's MFMA phase --
//    R4's regression was 2 blocks/CU).
//    Block: 256 thr = 4 waves; wave owns 64 rows: A = 4 row-frags x K=256 in
//    registers (128 regs, asm-pinned). Each B frag feeds 4 MFMA.
//    B panels staged whole (contiguous 16KB global_load_lds, linear src+dst),
//    double-buffered; k-major layout -> every ds_read_b128 linear-in-lane,
//    zero bank conflicts (verified R4: SQ_LDS_BANK_CONFLICT=0).
//    MFMA 16x16x32_bf16 C layout: col=lane&15, row=(lane>>4)*4+q  [verified].
// ---------------------------------------------------------------------------
__global__ void __launch_bounds__(256, 2) fused_kernel(
    const __hip_bfloat16* __restrict__ a_n, const __hip_bfloat16* __restrict__ p_k,
    const __hip_bfloat16* __restrict__ n_k, float* __restrict__ rowsum) {
  __shared__ __align__(16) __hip_bfloat16 smem[2][32 * DIM];   // 2 x 16KB
  const int tid  = threadIdx.x;
  const int lane = tid & 63;
  const int w    = tid >> 6;          // 0..3
  const int rb   = blockIdx.x >> 5;   // 0..31 (256 rows each)
  const int cc   = blockIdx.x & 31;   // 0..31 (512 cols = 16 panels each)
  const __hip_bfloat16* B = (cc < 16)
      ? (p_k + (size_t)cc * 16 * (32 * DIM))
      : (n_k + (size_t)(cc - 16) * 16 * (32 * DIM));
  const int row0 = rb * 256 + w * 64;
  const int ar = lane & 15;           // fragment row/col index
  const int g  = lane >> 4;           // k-group within fragment

  // A fragments: 64 rows x K=256, register-resident, pinned.
  bf16x8 afrag[4][8];
#pragma unroll
  for (int rf = 0; rf < 4; ++rf)
#pragma unroll
    for (int kk = 0; kk < 8; ++kk) {
      afrag[rf][kk] = *reinterpret_cast<const bf16x8*>(
          a_n + (size_t)(row0 + rf * 16 + ar) * DIM + kk * 32 + g * 8);
      asm volatile("" : "+v"(afrag[rf][kk]));   // non-remat def: stays in regs
    }

  // Stage panel `it` (16384 B contiguous) into smem[buf]: linear src+dst.
  // 4 waves x 4 chunks of 1KB each; dst base wave-uniform, lane offset x16.
#define STAGE(buf, it)                                                         \
  {                                                                            \
    _Pragma("unroll")                                                          \
    for (int j = 0; j < 4; ++j) {                                              \
      const int chunk = (w << 2) | j;                                          \
      const char* src = (const char*)B + (size_t)(it) * 16384 +                \
                        (chunk << 10) + (lane << 4);                           \
      char* dst = (char*)(&smem[buf][0]) + (chunk << 10);                      \
      __builtin_amdgcn_global_load_lds(                                        \
          (const __attribute__((address_space(1))) void*)src,                  \
          (__attribute__((address_space(3))) void*)dst, 16, 0, 0);             \
    }                                                                          \
  }

  float psum[4][4];
#pragma unroll
  for (int rf = 0; rf < 4; ++rf)
#pragma unroll
    for (int q = 0; q < 4; ++q) psum[rf][q] = 0.f;

  STAGE(0, 0);
  __syncthreads();
  int cur = 0;
  for (int it = 0; it < 16; ++it) {
    if (it < 15) STAGE(cur ^ 1, it + 1);   // prefetch next panel (overlaps MFMA)
    const char* bb = (const char*)(&smem[cur][0]) + (g << 9) + (ar << 4);
#pragma unroll
    for (int cf = 0; cf < 2; ++cf) {
      f32x4 acc[4];
#pragma unroll
      for (int rf = 0; rf < 4; ++rf) acc[rf] = (f32x4){0.f, 0.f, 0.f, 0.f};
#pragma unroll
      for (int kk = 0; kk < 8; ++kk) {
        // chunk (k0 = kk*4+g, col = cf*16+ar): byte = kk*2048 + g*512 + cf*256 + ar*16
        bf16x8 bf = *reinterpret_cast<const bf16x8*>(bb + (kk << 11) + (cf << 8));
#pragma unroll
        for (int rf = 0; rf < 4; ++rf)
          acc[rf] = __builtin_amdgcn_mfma_f32_16x16x32_bf16(afrag[rf][kk], bf, acc[rf], 0, 0, 0);
      }
      // acc = cos * 20*log2(e): logits bounded -> direct exp2, no max needed.
#pragma unroll
      for (int rf = 0; rf < 4; ++rf)
#pragma unroll
        for (int q = 0; q < 4; ++q)
          psum[rf][q] += __builtin_amdgcn_exp2f(acc[rf][q]);
    }
    __syncthreads();
    cur ^= 1;
  }

  // Reduce over the 16 column-lanes (vary ar, keep g) and accumulate per row.
#pragma unroll
  for (int rf = 0; rf < 4; ++rf)
#pragma unroll
    for (int q = 0; q < 4; ++q) {
      float s = psum[rf][q];
      s += __shfl_xor(s, 1);
      s += __shfl_xor(s, 2);
      s += __shfl_xor(s, 4);
      s += __shfl_xor(s, 8);
      if (ar == 0)
        atomicAdd(rowsum + row0 + rf * 16 + g * 4 + q, s);
    }
}

// ---------------------------------------------------------------------------
// 4) loss = mean_i( log(rowsum[i]) - diag[i] )
// ---------------------------------------------------------------------------
__global__ void __launch_bounds__(256) loss_kernel(
    const float* __restrict__ rowsum, const float* __restrict__ diag,
    float* __restrict__ out) {
  __shared__ float sh[4];
  float acc = 0.f;
  for (int i = threadIdx.x; i < N_ROWS; i += 256)
    acc += logf(rowsum[i]) - diag[i];
#pragma unroll
  for (int m = 32; m; m >>= 1) acc += __shfl_xor(acc, m);
  if ((threadIdx.x & 63) == 0) sh[threadIdx.x >> 6] = acc;
  __syncthreads();
  if (threadIdx.x == 0) out[0] = (sh[0] + sh[1] + sh[2] + sh[3]) / (float)N_ROWS;
}

// ---------------------------------------------------------------------------
extern "C" void kernel_launch(void* const* d_in, const int* in_sizes, int n_in,
                              void* d_out, int out_size, void* d_ws, size_t ws_size,
                              hipStream_t stream) {
  const float* anc = (const float*)d_in[0];
  const float* pos = (const float*)d_in[1];
  const float* neg = (const float*)d_in[2];
  char* ws = (char*)d_ws;
  __hip_bfloat16* a_n = (__hip_bfloat16*)ws;                 // [8192][256] bf16 row-major
  __hip_bfloat16* p_k = a_n + (size_t)N_ROWS * DIM;          // k-major panels
  __hip_bfloat16* n_k = p_k + (size_t)N_ROWS * DIM;
  float* diag = (float*)(ws + (size_t)3 * N_ROWS * DIM * 2); // 8192 f32
  float* rowsum = diag + N_ROWS;                             // 8192 f32
  float* out = (float*)d_out;

  prep_kernel<<<N_ROWS / 4, 256, 0, stream>>>(anc, pos, a_n, diag, rowsum);
  norm_t_kernel<<<2 * N_ROWS / 32, 256, 0, stream>>>(pos, neg, p_k, n_k);
  fused_kernel<<<32 * 32, 256, 0, stream>>>(a_n, p_k, n_k, rowsum);
  loss_kernel<<<1, 256, 0, stream>>>(rowsum, diag, out);
}

// Round 6
// 90.041 us; speedup vs baseline: 1.1124x; 1.0383x over previous
//
#include <hip/hip_runtime.h>
#include <hip/hip_bf16.h>

#define N_ROWS 8192
#define DIM 256
#define TEMP_INV 20.0f
// exp(cos/T) = exp2(cos * 20*log2(e)); anchor rows are PRE-SCALED by this so
// the fused epilogue is a bare v_exp on the MFMA accumulator.
#define EXP_SCALE 28.853900817779268f

typedef __attribute__((ext_vector_type(8))) short bf16x8;
typedef __attribute__((ext_vector_type(4))) float f32x4;

// ---------------------------------------------------------------------------
// 1) Merged prep:
//    blocks [0,2048): anchor rows -- a_n = anc*EXP_SCALE/||anc|| (bf16),
//                     diag = cos(anc,pos)/TEMP (f32 originals), rowsum = 0.
//    blocks [2048,2560): P/N panels -- L2-normalize + transpose to k-major
//                     panels (32 cols; 16B chunk idx = k0*32+col). Fused
//                     reads of this layout are linear-in-lane (0 conflicts,
//                     verified R4/R5) and staging is contiguous 16KB.
// ---------------------------------------------------------------------------
__global__ void __launch_bounds__(256) prep_kernel(
    const float* __restrict__ anc, const float* __restrict__ pos,
    const float* __restrict__ neg, __hip_bfloat16* __restrict__ a_n,
    __hip_bfloat16* __restrict__ p_k, __hip_bfloat16* __restrict__ n_k,
    float* __restrict__ diag, float* __restrict__ rowsum) {
  __shared__ __align__(16) __hip_bfloat16 t[32 * DIM];   // 16KB (panel path)
  const int lane = threadIdx.x & 63;
  const int w = threadIdx.x >> 6;

  if (blockIdx.x < 2048) {                   // ---- anchor rows ----
    int wid = blockIdx.x * 4 + w;            // row 0..8191
    float4 a = reinterpret_cast<const float4*>(anc + (size_t)wid * DIM)[lane];
    float4 p = reinterpret_cast<const float4*>(pos + (size_t)wid * DIM)[lane];
    float d  = a.x * p.x + a.y * p.y + a.z * p.z + a.w * p.w;
    float na = a.x * a.x + a.y * a.y + a.z * a.z + a.w * a.w;
    float np = p.x * p.x + p.y * p.y + p.z * p.z + p.w * p.w;
#pragma unroll
    for (int m = 32; m; m >>= 1) {
      d  += __shfl_xor(d, m);
      na += __shfl_xor(na, m);
      np += __shfl_xor(np, m);
    }
    float rna = fmaxf(sqrtf(na), 1e-8f);
    float scale = EXP_SCALE / rna;
    union { __hip_bfloat16 h[4]; uint2 u; } pk;
    pk.h[0] = __float2bfloat16(a.x * scale);
    pk.h[1] = __float2bfloat16(a.y * scale);
    pk.h[2] = __float2bfloat16(a.z * scale);
    pk.h[3] = __float2bfloat16(a.w * scale);
    reinterpret_cast<uint2*>(a_n + (size_t)wid * DIM)[lane] = pk.u;
    if (lane == 0) {
      diag[wid] = TEMP_INV * d / (rna * fmaxf(sqrtf(np), 1e-8f));
      rowsum[wid] = 0.f;
    }
    return;
  }
  // ---- P/N k-major panels ----
  const int b = blockIdx.x - 2048;           // 0..511
  const float* src = (b < 256) ? pos : neg;
  __hip_bfloat16* dst = (b < 256) ? p_k : n_k;
  const int pb = b & 255;
#pragma unroll
  for (int i = 0; i < 8; ++i) {
    int r = i * 4 + w;                       // row (col of B) within panel
    float4 v = reinterpret_cast<const float4*>(src + (size_t)(pb * 32 + r) * DIM)[lane];
    float ss = v.x * v.x + v.y * v.y + v.z * v.z + v.w * v.w;
#pragma unroll
    for (int m = 32; m; m >>= 1) ss += __shfl_xor(ss, m);
    float scale = 1.0f / fmaxf(sqrtf(ss), 1e-8f);
    union { __hip_bfloat16 h[4]; uint2 u; } pk;
    pk.h[0] = __float2bfloat16(v.x * scale);
    pk.h[1] = __float2bfloat16(v.y * scale);
    pk.h[2] = __float2bfloat16(v.z * scale);
    pk.h[3] = __float2bfloat16(v.w * scale);
    // lane holds k = 4*lane..4*lane+3  ->  k0 = lane>>1, half = lane&1
    char* p = (char*)t + ((((lane >> 1) * 32) + r) << 4) + ((lane & 1) << 3);
    *reinterpret_cast<uint2*>(p) = pk.u;
  }
  __syncthreads();
  const uint4* ts = reinterpret_cast<const uint4*>(t);
  uint4* out = reinterpret_cast<uint4*>(dst + (size_t)pb * (32 * DIM));
#pragma unroll
  for (int j = 0; j < 4; ++j)
    out[threadIdx.x + j * 256] = ts[threadIdx.x + j * 256];
}

// ---------------------------------------------------------------------------
// 2) Fused GEMM + row-wise sum(exp2(logit)) -- counted-vmcnt pipeline.
//    Grid: 32 row-blocks (BM=256) x 32 col-chunks (512 cols = 16 panels).
//    Block: 256 thr = 4 waves; wave owns 64 rows (A = 4 rf x K=256 in regs,
//    asm-pinned). B panels (16KB, k-major) in a 3-buffer LDS ring (48KB),
//    prefetch depth 2 via contiguous global_load_lds (4 loads/wave/panel).
//    Pipeline discipline (T3+T4): per iteration exactly ONE raw s_barrier and
//    ONE s_waitcnt vmcnt(4) -- "own loads for panel it done, panel it+1 still
//    in flight". No vmcnt(0) drain in the main loop (that drain was R5's
//    ~900 TF ceiling). WAR on the ring buffer is safe: reads of the buffer
//    being overwritten finished before the PREVIOUS barrier (lgkmcnt(0)
//    precedes the MFMAs that precede barrier arrival).
//    T5: setprio(1) around each MFMA cluster (phase-split schedule).
//    MFMA 16x16x32_bf16 C layout: col=lane&15, row=(lane>>4)*4+q  [verified].
// ---------------------------------------------------------------------------
__global__ void __launch_bounds__(256, 4) fused_kernel(
    const __hip_bfloat16* __restrict__ a_n, const __hip_bfloat16* __restrict__ p_k,
    const __hip_bfloat16* __restrict__ n_k, float* __restrict__ rowsum) {
  __shared__ __align__(16) __hip_bfloat16 smem[3][32 * DIM];   // 3 x 16KB ring
  const int tid  = threadIdx.x;
  const int lane = tid & 63;
  const int w    = tid >> 6;          // 0..3
  const int rb   = blockIdx.x >> 5;   // 0..31 (256 rows each)
  const int cc   = blockIdx.x & 31;   // 0..31 (512 cols = 16 panels each)
  const __hip_bfloat16* B = (cc < 16)
      ? (p_k + (size_t)cc * 16 * (32 * DIM))
      : (n_k + (size_t)(cc - 16) * 16 * (32 * DIM));
  const int row0 = rb * 256 + w * 64;
  const int ar = lane & 15;           // fragment row/col index
  const int g  = lane >> 4;           // k-group within fragment

  // A fragments: 64 rows x K=256, register-resident, pinned.
  bf16x8 afrag[4][8];
#pragma unroll
  for (int rf = 0; rf < 4; ++rf)
#pragma unroll
    for (int kk = 0; kk < 8; ++kk) {
      afrag[rf][kk] = *reinterpret_cast<const bf16x8*>(
          a_n + (size_t)(row0 + rf * 16 + ar) * DIM + kk * 32 + g * 8);
      asm volatile("" : "+v"(afrag[rf][kk]));   // non-remat def: stays in regs
    }

  // Stage panel `it` (16384 B contiguous) into ring buffer `buf`.
#define STAGE(buf, it)                                                         \
  {                                                                            \
    _Pragma("unroll")                                                          \
    for (int j = 0; j < 4; ++j) {                                              \
      const int chunk = (w << 2) | j;                                          \
      const char* src = (const char*)B + (size_t)(it) * 16384 +                \
                        (chunk << 10) + (lane << 4);                           \
      char* dst = (char*)(&smem[0][0]) + (buf) * 16384 + (chunk << 10);        \
      __builtin_amdgcn_global_load_lds(                                        \
          (const __attribute__((address_space(1))) void*)src,                  \
          (__attribute__((address_space(3))) void*)dst, 16, 0, 0);             \
    }                                                                          \
  }

  // One panel's compute: 16 ds_read_b128 + 64 MFMA + 32 exp2.
#define COMPUTE(bb)                                                            \
  {                                                                            \
    _Pragma("unroll")                                                          \
    for (int cf = 0; cf < 2; ++cf) {                                           \
      f32x4 acc[4];                                                            \
      _Pragma("unroll")                                                        \
      for (int rf = 0; rf < 4; ++rf) acc[rf] = (f32x4){0.f, 0.f, 0.f, 0.f};    \
      __builtin_amdgcn_s_setprio(1);                                           \
      _Pragma("unroll")                                                        \
      for (int kk = 0; kk < 8; ++kk) {                                         \
        bf16x8 bf = *reinterpret_cast<const bf16x8*>((bb) + (kk << 11) + (cf << 8)); \
        _Pragma("unroll")                                                      \
        for (int rf = 0; rf < 4; ++rf)                                         \
          acc[rf] = __builtin_amdgcn_mfma_f32_16x16x32_bf16(afrag[rf][kk], bf, acc[rf], 0, 0, 0); \
      }                                                                        \
      __builtin_amdgcn_s_setprio(0);                                           \
      _Pragma("unroll")                                                        \
      for (int rf = 0; rf < 4; ++rf)                                           \
        _Pragma("unroll")                                                      \
        for (int q = 0; q < 4; ++q)                                            \
          psum[rf][q] += __builtin_amdgcn_exp2f(acc[rf][q]);                   \
    }                                                                          \
  }

  float psum[4][4];
#pragma unroll
  for (int rf = 0; rf < 4; ++rf)
#pragma unroll
    for (int q = 0; q < 4; ++q) psum[rf][q] = 0.f;

  STAGE(0, 0);
  STAGE(1, 1);
  for (int it = 0; it < 15; ++it) {
    // Own loads for panel `it` complete (4 newer ones may stay in flight).
    asm volatile("s_waitcnt vmcnt(4)" ::: "memory");
    __builtin_amdgcn_s_barrier();
    asm volatile("" ::: "memory");
    if (it < 14) STAGE((it + 2) % 3, it + 2);
    const char* bb = (const char*)(&smem[0][0]) + (it % 3) * 16384 +
                     (g << 9) + (ar << 4);
    COMPUTE(bb);
  }
  // Last panel: drain everything.
  asm volatile("s_waitcnt vmcnt(0)" ::: "memory");
  __builtin_amdgcn_s_barrier();
  asm volatile("" ::: "memory");
  {
    const char* bb = (const char*)(&smem[0][0]) + (15 % 3) * 16384 +
                     (g << 9) + (ar << 4);
    COMPUTE(bb);
  }

  // Reduce over the 16 column-lanes (vary ar, keep g) and accumulate per row.
#pragma unroll
  for (int rf = 0; rf < 4; ++rf)
#pragma unroll
    for (int q = 0; q < 4; ++q) {
      float s = psum[rf][q];
      s += __shfl_xor(s, 1);
      s += __shfl_xor(s, 2);
      s += __shfl_xor(s, 4);
      s += __shfl_xor(s, 8);
      if (ar == 0)
        atomicAdd(rowsum + row0 + rf * 16 + g * 4 + q, s);
    }
#undef STAGE
#undef COMPUTE
}

// ---------------------------------------------------------------------------
// 3) loss = mean_i( log(rowsum[i]) - diag[i] )
// ---------------------------------------------------------------------------
__global__ void __launch_bounds__(1024) loss_kernel(
    const float* __restrict__ rowsum, const float* __restrict__ diag,
    float* __restrict__ out) {
  __shared__ float sh[16];
  float acc = 0.f;
  for (int i = threadIdx.x; i < N_ROWS; i += 1024)
    acc += logf(rowsum[i]) - diag[i];
#pragma unroll
  for (int m = 32; m; m >>= 1) acc += __shfl_xor(acc, m);
  if ((threadIdx.x & 63) == 0) sh[threadIdx.x >> 6] = acc;
  __syncthreads();
  if (threadIdx.x == 0) {
    float t = 0.f;
#pragma unroll
    for (int j = 0; j < 16; ++j) t += sh[j];
    out[0] = t / (float)N_ROWS;
  }
}

// ---------------------------------------------------------------------------
extern "C" void kernel_launch(void* const* d_in, const int* in_sizes, int n_in,
                              void* d_out, int out_size, void* d_ws, size_t ws_size,
                              hipStream_t stream) {
  const float* anc = (const float*)d_in[0];
  const float* pos = (const float*)d_in[1];
  const float* neg = (const float*)d_in[2];
  char* ws = (char*)d_ws;
  __hip_bfloat16* a_n = (__hip_bfloat16*)ws;                 // [8192][256] bf16 row-major
  __hip_bfloat16* p_k = a_n + (size_t)N_ROWS * DIM;          // k-major panels
  __hip_bfloat16* n_k = p_k + (size_t)N_ROWS * DIM;
  float* diag = (float*)(ws + (size_t)3 * N_ROWS * DIM * 2); // 8192 f32
  float* rowsum = diag + N_ROWS;                             // 8192 f32
  float* out = (float*)d_out;

  prep_kernel<<<2048 + 512, 256, 0, stream>>>(anc, pos, neg, a_n, p_k, n_k, diag, rowsum);
  fused_kernel<<<32 * 32, 256, 0, stream>>>(a_n, p_k, n_k, rowsum);
  loss_kernel<<<1, 1024, 0, stream>>>(rowsum, diag, out);
}

// Round 7
// 87.364 us; speedup vs baseline: 1.1465x; 1.0306x over previous
//
#include <hip/hip_runtime.h>
#include <hip/hip_bf16.h>

#define N_ROWS 8192
#define DIM 256
#define TEMP_INV 20.0f
// exp(cos/T) = exp2(cos * 20*log2(e)); anchor rows are PRE-SCALED by this so
// the fused epilogue is a bare v_exp on the MFMA accumulator.
#define EXP_SCALE 28.853900817779268f

typedef __attribute__((ext_vector_type(8))) short bf16x8;
typedef __attribute__((ext_vector_type(4))) float f32x4;

// ---------------------------------------------------------------------------
// 1) Merged prep:
//    blocks [0,2048): anchor rows -- a_n = anc*EXP_SCALE/||anc|| (bf16),
//                     diag = cos(anc,pos)/TEMP (f32 originals), rowsum = 0.
//    blocks [2048,2560): P/N panels -- L2-normalize + transpose to k-major
//                     panels (32 cols; 16B chunk idx = k0*32+col, k0=k/8).
// ---------------------------------------------------------------------------
__global__ void __launch_bounds__(256) prep_kernel(
    const float* __restrict__ anc, const float* __restrict__ pos,
    const float* __restrict__ neg, __hip_bfloat16* __restrict__ a_n,
    __hip_bfloat16* __restrict__ p_k, __hip_bfloat16* __restrict__ n_k,
    float* __restrict__ diag, float* __restrict__ rowsum) {
  __shared__ __align__(16) __hip_bfloat16 t[32 * DIM];   // 16KB (panel path)
  const int lane = threadIdx.x & 63;
  const int w = threadIdx.x >> 6;

  if (blockIdx.x < 2048) {                   // ---- anchor rows ----
    int wid = blockIdx.x * 4 + w;            // row 0..8191
    float4 a = reinterpret_cast<const float4*>(anc + (size_t)wid * DIM)[lane];
    float4 p = reinterpret_cast<const float4*>(pos + (size_t)wid * DIM)[lane];
    float d  = a.x * p.x + a.y * p.y + a.z * p.z + a.w * p.w;
    float na = a.x * a.x + a.y * a.y + a.z * a.z + a.w * a.w;
    float np = p.x * p.x + p.y * p.y + p.z * p.z + p.w * p.w;
#pragma unroll
    for (int m = 32; m; m >>= 1) {
      d  += __shfl_xor(d, m);
      na += __shfl_xor(na, m);
      np += __shfl_xor(np, m);
    }
    float rna = fmaxf(sqrtf(na), 1e-8f);
    float scale = EXP_SCALE / rna;
    union { __hip_bfloat16 h[4]; uint2 u; } pk;
    pk.h[0] = __float2bfloat16(a.x * scale);
    pk.h[1] = __float2bfloat16(a.y * scale);
    pk.h[2] = __float2bfloat16(a.z * scale);
    pk.h[3] = __float2bfloat16(a.w * scale);
    reinterpret_cast<uint2*>(a_n + (size_t)wid * DIM)[lane] = pk.u;
    if (lane == 0) {
      diag[wid] = TEMP_INV * d / (rna * fmaxf(sqrtf(np), 1e-8f));
      rowsum[wid] = 0.f;
    }
    return;
  }
  // ---- P/N k-major panels ----
  const int b = blockIdx.x - 2048;           // 0..511
  const float* src = (b < 256) ? pos : neg;
  __hip_bfloat16* dst = (b < 256) ? p_k : n_k;
  const int pb = b & 255;
#pragma unroll
  for (int i = 0; i < 8; ++i) {
    int r = i * 4 + w;                       // row (col of B) within panel
    float4 v = reinterpret_cast<const float4*>(src + (size_t)(pb * 32 + r) * DIM)[lane];
    float ss = v.x * v.x + v.y * v.y + v.z * v.z + v.w * v.w;
#pragma unroll
    for (int m = 32; m; m >>= 1) ss += __shfl_xor(ss, m);
    float scale = 1.0f / fmaxf(sqrtf(ss), 1e-8f);
    union { __hip_bfloat16 h[4]; uint2 u; } pk;
    pk.h[0] = __float2bfloat16(v.x * scale);
    pk.h[1] = __float2bfloat16(v.y * scale);
    pk.h[2] = __float2bfloat16(v.z * scale);
    pk.h[3] = __float2bfloat16(v.w * scale);
    // lane holds k = 4*lane..4*lane+3  ->  k0 = lane>>1, half = lane&1
    char* p = (char*)t + ((((lane >> 1) * 32) + r) << 4) + ((lane & 1) << 3);
    *reinterpret_cast<uint2*>(p) = pk.u;
  }
  __syncthreads();
  const uint4* ts = reinterpret_cast<const uint4*>(t);
  uint4* out = reinterpret_cast<uint4*>(dst + (size_t)pb * (32 * DIM));
#pragma unroll
  for (int j = 0; j < 4; ++j)
    out[threadIdx.x + j * 256] = ts[threadIdx.x + j * 256];
}

// ---------------------------------------------------------------------------
// 2) Fused GEMM + row-wise sum(exp2(logit)) -- NO LDS, NO BARRIERS.
//    Rationale: K=256 means A lives permanently in registers (128 VGPR,
//    asm-pinned); only B streams. The 4 waves of a block read the SAME
//    k-major B panel stream -> L1-served (32KB holds 2 panels); each XCD's
//    blocks share cc%8 -> B working set ~1MB, L2-resident. B-demand at full
//    MFMA rate = 3378 FLOP/cy / 64 rows = 53 B/cy/CU, mostly L1. Removing
//    every barrier/vmcnt(0) eliminates the 2-phase ~900 TF structural
//    ceiling (R4-R6 all pinned at it).
//    B register double-buffer at half-panel granularity: 8 x bf16x8
//    (32 VGPR) per buffer; load-use distance = one 32-MFMA cluster.
//    Cluster c (0..31): panel p=c>>1, cf=c&1 (16 output cols each).
//    Total VGPR ~ 128(A)+64(B)+16(acc)+16(psum)+addr ~ 240 -> 2 waves/SIMD.
//    MFMA 16x16x32_bf16 C layout: col=lane&15, row=(lane>>4)*4+q  [verified].
// ---------------------------------------------------------------------------
__global__ void __launch_bounds__(256, 2) fused_kernel(
    const __hip_bfloat16* __restrict__ a_n, const __hip_bfloat16* __restrict__ p_k,
    const __hip_bfloat16* __restrict__ n_k, float* __restrict__ rowsum) {
  const int tid  = threadIdx.x;
  const int lane = tid & 63;
  const int w    = tid >> 6;          // 0..3
  const int rb   = blockIdx.x >> 5;   // 0..31 (256 rows each)
  const int cc   = blockIdx.x & 31;   // 0..31 (512 cols = 16 panels each)
  const char* B = (const char*)((cc < 16)
      ? (p_k + (size_t)cc * 16 * (32 * DIM))
      : (n_k + (size_t)(cc - 16) * 16 * (32 * DIM)));
  const int row0 = rb * 256 + w * 64;
  const int ar = lane & 15;           // fragment row/col index
  const int g  = lane >> 4;           // k-group within fragment
  const int vbase = (g << 9) + (ar << 4);  // lane byte-offset within a cluster

  // cluster c byte base (before lane offset): (c>>1)*16384 + (c&1)*256
#define CLUSTER_PTR(c) (B + ((size_t)((c) >> 1) << 14) + (((c) & 1) << 8) + vbase)

  // A fragments: 64 rows x K=256, register-resident, pinned.
  bf16x8 afrag[4][8];
#pragma unroll
  for (int rf = 0; rf < 4; ++rf)
#pragma unroll
    for (int kk = 0; kk < 8; ++kk) {
      afrag[rf][kk] = *reinterpret_cast<const bf16x8*>(
          a_n + (size_t)(row0 + rf * 16 + ar) * DIM + kk * 32 + g * 8);
      asm volatile("" : "+v"(afrag[rf][kk]));   // non-remat def: stays in regs
    }

  float psum[4][4];
#pragma unroll
  for (int rf = 0; rf < 4; ++rf)
#pragma unroll
    for (int q = 0; q < 4; ++q) psum[rf][q] = 0.f;

  // One cluster's compute: 32 MFMA, then refill the SAME buffer with cluster
  // `nc` (loads issue after the last MFMA reading the buffer; their latency
  // hides under the next cluster's MFMAs), then 16 exp2 + psum adds.
#define STEP(buf, nc)                                                          \
  {                                                                            \
    f32x4 acc[4];                                                              \
    _Pragma("unroll")                                                          \
    for (int rf = 0; rf < 4; ++rf) acc[rf] = (f32x4){0.f, 0.f, 0.f, 0.f};      \
    _Pragma("unroll")                                                          \
    for (int kk = 0; kk < 8; ++kk)                                             \
      _Pragma("unroll")                                                        \
      for (int rf = 0; rf < 4; ++rf)                                           \
        acc[rf] = __builtin_amdgcn_mfma_f32_16x16x32_bf16(afrag[rf][kk], buf[kk], acc[rf], 0, 0, 0); \
    const char* nsrc = CLUSTER_PTR(nc);                                        \
    _Pragma("unroll")                                                          \
    for (int kk = 0; kk < 8; ++kk)                                             \
      buf[kk] = *reinterpret_cast<const bf16x8*>(nsrc + (kk << 11));           \
    _Pragma("unroll")                                                          \
    for (int rf = 0; rf < 4; ++rf)                                             \
      _Pragma("unroll")                                                        \
      for (int q = 0; q < 4; ++q)                                              \
        psum[rf][q] += __builtin_amdgcn_exp2f(acc[rf][q]);                     \
  }

  // Prologue: clusters 0 and 1.
  bf16x8 bufA[8], bufB[8];
  {
    const char* s0 = CLUSTER_PTR(0);
    const char* s1 = CLUSTER_PTR(1);
#pragma unroll
    for (int kk = 0; kk < 8; ++kk) {
      bufA[kk] = *reinterpret_cast<const bf16x8*>(s0 + (kk << 11));
      bufB[kk] = *reinterpret_cast<const bf16x8*>(s1 + (kk << 11));
    }
  }

  for (int i = 0; i < 16; ++i) {   // one panel (2 clusters) per iteration
    int ncA = i * 2 + 2; if (ncA > 31) ncA = 31;   // tail: harmless re-load
    int ncB = i * 2 + 3; if (ncB > 31) ncB = 31;
    STEP(bufA, ncA);
    STEP(bufB, ncB);
  }

  // Reduce over the 16 column-lanes (vary ar, keep g) and accumulate per row.
#pragma unroll
  for (int rf = 0; rf < 4; ++rf)
#pragma unroll
    for (int q = 0; q < 4; ++q) {
      float s = psum[rf][q];
      s += __shfl_xor(s, 1);
      s += __shfl_xor(s, 2);
      s += __shfl_xor(s, 4);
      s += __shfl_xor(s, 8);
      if (ar == 0)
        atomicAdd(rowsum + row0 + rf * 16 + g * 4 + q, s);
    }
#undef STEP
#undef CLUSTER_PTR
}

// ---------------------------------------------------------------------------
// 3) loss = mean_i( log(rowsum[i]) - diag[i] )
// ---------------------------------------------------------------------------
__global__ void __launch_bounds__(1024) loss_kernel(
    const float* __restrict__ rowsum, const float* __restrict__ diag,
    float* __restrict__ out) {
  __shared__ float sh[16];
  float acc = 0.f;
  for (int i = threadIdx.x; i < N_ROWS; i += 1024)
    acc += logf(rowsum[i]) - diag[i];
#pragma unroll
  for (int m = 32; m; m >>= 1) acc += __shfl_xor(acc, m);
  if ((threadIdx.x & 63) == 0) sh[threadIdx.x >> 6] = acc;
  __syncthreads();
  if (threadIdx.x == 0) {
    float t = 0.f;
#pragma unroll
    for (int j = 0; j < 16; ++j) t += sh[j];
    out[0] = t / (float)N_ROWS;
  }
}

// ---------------------------------------------------------------------------
extern "C" void kernel_launch(void* const* d_in, const int* in_sizes, int n_in,
                              void* d_out, int out_size, void* d_ws, size_t ws_size,
                              hipStream_t stream) {
  const float* anc = (const float*)d_in[0];
  const float* pos = (const float*)d_in[1];
  const float* neg = (const float*)d_in[2];
  char* ws = (char*)d_ws;
  __hip_bfloat16* a_n = (__hip_bfloat16*)ws;                 // [8192][256] bf16 row-major
  __hip_bfloat16* p_k = a_n + (size_t)N_ROWS * DIM;          // k-major panels
  __hip_bfloat16* n_k = p_k + (size_t)N_ROWS * DIM;
  float* diag = (float*)(ws + (size_t)3 * N_ROWS * DIM * 2); // 8192 f32
  float* rowsum = diag + N_ROWS;                             // 8192 f32
  float* out = (float*)d_out;

  prep_kernel<<<2048 + 512, 256, 0, stream>>>(anc, pos, neg, a_n, p_k, n_k, diag, rowsum);
  fused_kernel<<<32 * 32, 256, 0, stream>>>(a_n, p_k, n_k, rowsum);
  loss_kernel<<<1, 1024, 0, stream>>>(rowsum, diag, out);
}

// Round 8
// 86.410 us; speedup vs baseline: 1.1592x; 1.0110x over previous
//
#include <hip/hip_runtime.h>
#include <hip/hip_bf16.h>

#define N_ROWS 8192
#define DIM 256
#define TEMP_INV 20.0f
// exp(cos/T) = exp2(cos * 20*log2(e)); anchor rows are PRE-SCALED by this so
// the fused epilogue is a bare v_exp on the MFMA accumulator.
#define EXP_SCALE 28.853900817779268f

typedef __attribute__((ext_vector_type(8))) short bf16x8;
typedef __attribute__((ext_vector_type(4))) float f32x4;

// ---------------------------------------------------------------------------
// 1) Merged prep:
//    blocks [0,2048): anchor rows -- a_n = anc*EXP_SCALE/||anc|| (bf16),
//                     diag = cos(anc,pos)/TEMP (f32 originals), rowsum = 0.
//    blocks [2048,2560): P/N panels -- L2-normalize + transpose to k-major
//                     panels (32 cols; 16B chunk idx = k0*32+col, k0=k/8).
//    block 2559 thread 0 additionally zero-inits out[0] (loss accumulates
//    atomically).
// ---------------------------------------------------------------------------
__global__ void __launch_bounds__(256) prep_kernel(
    const float* __restrict__ anc, const float* __restrict__ pos,
    const float* __restrict__ neg, __hip_bfloat16* __restrict__ a_n,
    __hip_bfloat16* __restrict__ p_k, __hip_bfloat16* __restrict__ n_k,
    float* __restrict__ diag, float* __restrict__ rowsum,
    float* __restrict__ out) {
  __shared__ __align__(16) __hip_bfloat16 t[32 * DIM];   // 16KB (panel path)
  const int lane = threadIdx.x & 63;
  const int w = threadIdx.x >> 6;

  if (blockIdx.x < 2048) {                   // ---- anchor rows ----
    int wid = blockIdx.x * 4 + w;            // row 0..8191
    float4 a = reinterpret_cast<const float4*>(anc + (size_t)wid * DIM)[lane];
    float4 p = reinterpret_cast<const float4*>(pos + (size_t)wid * DIM)[lane];
    float d  = a.x * p.x + a.y * p.y + a.z * p.z + a.w * p.w;
    float na = a.x * a.x + a.y * a.y + a.z * a.z + a.w * a.w;
    float np = p.x * p.x + p.y * p.y + p.z * p.z + p.w * p.w;
#pragma unroll
    for (int m = 32; m; m >>= 1) {
      d  += __shfl_xor(d, m);
      na += __shfl_xor(na, m);
      np += __shfl_xor(np, m);
    }
    float rna = fmaxf(sqrtf(na), 1e-8f);
    float scale = EXP_SCALE / rna;
    union { __hip_bfloat16 h[4]; uint2 u; } pk;
    pk.h[0] = __float2bfloat16(a.x * scale);
    pk.h[1] = __float2bfloat16(a.y * scale);
    pk.h[2] = __float2bfloat16(a.z * scale);
    pk.h[3] = __float2bfloat16(a.w * scale);
    reinterpret_cast<uint2*>(a_n + (size_t)wid * DIM)[lane] = pk.u;
    if (lane == 0) {
      diag[wid] = TEMP_INV * d / (rna * fmaxf(sqrtf(np), 1e-8f));
      rowsum[wid] = 0.f;
    }
    return;
  }
  // ---- P/N k-major panels ----
  const int b = blockIdx.x - 2048;           // 0..511
  if (b == 511 && threadIdx.x == 0) out[0] = 0.f;
  const float* src = (b < 256) ? pos : neg;
  __hip_bfloat16* dst = (b < 256) ? p_k : n_k;
  const int pb = b & 255;
#pragma unroll
  for (int i = 0; i < 8; ++i) {
    int r = i * 4 + w;                       // row (col of B) within panel
    float4 v = reinterpret_cast<const float4*>(src + (size_t)(pb * 32 + r) * DIM)[lane];
    float ss = v.x * v.x + v.y * v.y + v.z * v.z + v.w * v.w;
#pragma unroll
    for (int m = 32; m; m >>= 1) ss += __shfl_xor(ss, m);
    float scale = 1.0f / fmaxf(sqrtf(ss), 1e-8f);
    union { __hip_bfloat16 h[4]; uint2 u; } pk;
    pk.h[0] = __float2bfloat16(v.x * scale);
    pk.h[1] = __float2bfloat16(v.y * scale);
    pk.h[2] = __float2bfloat16(v.z * scale);
    pk.h[3] = __float2bfloat16(v.w * scale);
    // lane holds k = 4*lane..4*lane+3  ->  k0 = lane>>1, half = lane&1
    char* p = (char*)t + ((((lane >> 1) * 32) + r) << 4) + ((lane & 1) << 3);
    *reinterpret_cast<uint2*>(p) = pk.u;
  }
  __syncthreads();
  const uint4* ts = reinterpret_cast<const uint4*>(t);
  uint4* outp = reinterpret_cast<uint4*>(dst + (size_t)pb * (32 * DIM));
#pragma unroll
  for (int j = 0; j < 4; ++j)
    outp[threadIdx.x + j * 256] = ts[threadIdx.x + j * 256];
}

// ---------------------------------------------------------------------------
// 2) Fused GEMM + row-wise sum(exp2(logit)) -- m201-template port.
//    Grid: 16 row-blocks (BM=512) x 32 col-chunks (512 cols = 16 panels)
//    = 512 blocks (2 clean rounds over 256 CUs).
//    Block: 512 thr = 8 waves (single barrier domain, like the proven
//    m201 8-phase kernel); wave owns 64 rows (A = 4 rf x K=256 pinned ->
//    AGPR-resident, R7-verified). B panels (16KB, k-major) in a RING-of-4
//    LDS buffer (64KB), prefetch depth 3 via contiguous global_load_lds
//    (2 loads/wave/panel).
//    Schedule per panel (T3+T4+T5, faithful): counted s_waitcnt vmcnt(4)
//    (NEVER 0 in steady state; exact 4/2/0 tail), ONE s_barrier, then two
//    sub-phases: {8 ds_read_b128; [issue STAGE it+3 -- fine interleave];
//    setprio(1) 32 MFMA setprio(0); 16 exp2}.
//    WAR on ring slot (it+3)&3: reads of panel it-1 completed by every wave
//    before it reached barrier(it); STAGE issues after barrier(it). Safe.
//    k-major layout -> ds_reads linear-in-lane, 0 conflicts (R4-R7 verified).
//    MFMA 16x16x32_bf16 C layout: col=lane&15, row=(lane>>4)*4+q  [verified].
// ---------------------------------------------------------------------------
__global__ void __launch_bounds__(512, 2) fused_kernel(
    const __hip_bfloat16* __restrict__ a_n, const __hip_bfloat16* __restrict__ p_k,
    const __hip_bfloat16* __restrict__ n_k, float* __restrict__ rowsum) {
  __shared__ __align__(16) char smem[4 * 16384];   // ring of 4 x 16KB panels
  const int tid  = threadIdx.x;
  const int lane = tid & 63;
  const int w    = tid >> 6;          // 0..7
  const int rb   = blockIdx.x >> 5;   // 0..15 (512 rows each)
  const int cc   = blockIdx.x & 31;   // 0..31 (512 cols = 16 panels each)
  const char* B = (const char*)((cc < 16)
      ? (p_k + (size_t)cc * 16 * (32 * DIM))
      : (n_k + (size_t)(cc - 16) * 16 * (32 * DIM)));
  const int row0 = rb * 512 + w * 64;
  const int ar = lane & 15;           // fragment row/col index
  const int g  = lane >> 4;           // k-group within fragment
  const int vbase = (g << 9) + (ar << 4);  // lane byte-offset within a panel

  // A fragments: 64 rows x K=256, register(AGPR)-resident, pinned.
  bf16x8 afrag[4][8];
#pragma unroll
  for (int rf = 0; rf < 4; ++rf)
#pragma unroll
    for (int kk = 0; kk < 8; ++kk) {
      afrag[rf][kk] = *reinterpret_cast<const bf16x8*>(
          a_n + (size_t)(row0 + rf * 16 + ar) * DIM + kk * 32 + g * 8);
      asm volatile("" : "+v"(afrag[rf][kk]));   // non-remat def: stays resident
    }

  // Stage panel `p` (16KB contiguous) into ring slot p&3: 2 loads/wave.
#define STAGE(p)                                                               \
  {                                                                            \
    _Pragma("unroll")                                                          \
    for (int j = 0; j < 2; ++j) {                                              \
      const int L = (w << 1) | j;                                              \
      const char* src = B + ((size_t)(p) << 14) + (L << 10) + (lane << 4);     \
      char* dst = (char*)smem + (((p) & 3) << 14) + (L << 10);                 \
      __builtin_amdgcn_global_load_lds(                                        \
          (const __attribute__((address_space(1))) void*)src,                  \
          (__attribute__((address_space(3))) void*)dst, 16, 0, 0);             \
    }                                                                          \
  }

  // One sub-phase: 8 ds_read_b128 + optional STAGE + 32 MFMA + 16 exp2.
#define PHASE(pbase, cf, do_stage, it)                                         \
  {                                                                            \
    bf16x8 bf[8];                                                              \
    _Pragma("unroll")                                                          \
    for (int kk = 0; kk < 8; ++kk)                                             \
      bf[kk] = *reinterpret_cast<const bf16x8*>((pbase) + (kk << 11) + ((cf) << 8)); \
    if (do_stage) STAGE((it) + 3);                                             \
    f32x4 acc[4];                                                              \
    _Pragma("unroll")                                                          \
    for (int rf = 0; rf < 4; ++rf) acc[rf] = (f32x4){0.f, 0.f, 0.f, 0.f};      \
    __builtin_amdgcn_s_setprio(1);                                             \
    _Pragma("unroll")                                                          \
    for (int kk = 0; kk < 8; ++kk)                                             \
      _Pragma("unroll")                                                        \
      for (int rf = 0; rf < 4; ++rf)                                           \
        acc[rf] = __builtin_amdgcn_mfma_f32_16x16x32_bf16(afrag[rf][kk], bf[kk], acc[rf], 0, 0, 0); \
    __builtin_amdgcn_s_setprio(0);                                             \
    _Pragma("unroll")                                                          \
    for (int rf = 0; rf < 4; ++rf)                                             \
      _Pragma("unroll")                                                        \
      for (int q = 0; q < 4; ++q)                                              \
        psum[rf][q] += __builtin_amdgcn_exp2f(acc[rf][q]);                     \
  }

  float psum[4][4];
#pragma unroll
  for (int rf = 0; rf < 4; ++rf)
#pragma unroll
    for (int q = 0; q < 4; ++q) psum[rf][q] = 0.f;

  STAGE(0);
  STAGE(1);
  STAGE(2);   // 6 loads/wave outstanding
  for (int it = 0; it < 16; ++it) {
    // Counted waits: own panel-`it` loads (oldest 2) complete; newer panels
    // stay in flight. Steady state: panels it+1, it+2 in flight -> vmcnt(4).
    if (it <= 13)      asm volatile("s_waitcnt vmcnt(4)" ::: "memory");
    else if (it == 14) asm volatile("s_waitcnt vmcnt(2)" ::: "memory");
    else               asm volatile("s_waitcnt vmcnt(0)" ::: "memory");
    __builtin_amdgcn_s_barrier();
    const char* pbase = smem + ((it & 3) << 14) + vbase;
    PHASE(pbase, 0, it < 13, it);
    PHASE(pbase, 1, false, it);
  }

  // Reduce over the 16 column-lanes (vary ar, keep g) and accumulate per row.
#pragma unroll
  for (int rf = 0; rf < 4; ++rf)
#pragma unroll
    for (int q = 0; q < 4; ++q) {
      float s = psum[rf][q];
      s += __shfl_xor(s, 1);
      s += __shfl_xor(s, 2);
      s += __shfl_xor(s, 4);
      s += __shfl_xor(s, 8);
      if (ar == 0)
        atomicAdd(rowsum + row0 + rf * 16 + g * 4 + q, s);
    }
#undef STAGE
#undef PHASE
}

// ---------------------------------------------------------------------------
// 3) loss: grid 16 x 512 thr, one row per thread;
//    out[0] (+)= block-partials / N   (out zero-initialized in prep).
// ---------------------------------------------------------------------------
__global__ void __launch_bounds__(512) loss_kernel(
    const float* __restrict__ rowsum, const float* __restrict__ diag,
    float* __restrict__ out) {
  __shared__ float sh[8];
  int i = blockIdx.x * 512 + threadIdx.x;    // exactly covers 8192 rows
  float acc = logf(rowsum[i]) - diag[i];
#pragma unroll
  for (int m = 32; m; m >>= 1) acc += __shfl_xor(acc, m);
  if ((threadIdx.x & 63) == 0) sh[threadIdx.x >> 6] = acc;
  __syncthreads();
  if (threadIdx.x == 0) {
    float t = 0.f;
#pragma unroll
    for (int j = 0; j < 8; ++j) t += sh[j];
    atomicAdd(out, t / (float)N_ROWS);
  }
}

// ---------------------------------------------------------------------------
extern "C" void kernel_launch(void* const* d_in, const int* in_sizes, int n_in,
                              void* d_out, int out_size, void* d_ws, size_t ws_size,
                              hipStream_t stream) {
  const float* anc = (const float*)d_in[0];
  const float* pos = (const float*)d_in[1];
  const float* neg = (const float*)d_in[2];
  char* ws = (char*)d_ws;
  __hip_bfloat16* a_n = (__hip_bfloat16*)ws;                 // [8192][256] bf16 row-major
  __hip_bfloat16* p_k = a_n + (size_t)N_ROWS * DIM;          // k-major panels
  __hip_bfloat16* n_k = p_k + (size_t)N_ROWS * DIM;
  float* diag = (float*)(ws + (size_t)3 * N_ROWS * DIM * 2); // 8192 f32
  float* rowsum = diag + N_ROWS;                             // 8192 f32
  float* out = (float*)d_out;

  prep_kernel<<<2048 + 512, 256, 0, stream>>>(anc, pos, neg, a_n, p_k, n_k, diag, rowsum, out);
  fused_kernel<<<16 * 32, 512, 0, stream>>>(a_n, p_k, n_k, rowsum);
  loss_kernel<<<16, 512, 0, stream>>>(rowsum, diag, out);
}